// Round 11
// baseline (334.106 us; speedup 1.0000x reference)
//
#include <hip/hip_runtime.h>
#include <hip/hip_bf16.h>
#include <stdint.h>

// EvolvedLoopLinear: out[b,j] = sum_i x[b,i]*W[j,i] + b[j]
// M=8192, N=4096, K=4096. fp32 in/out, bf16 MFMA compute.
// Round 11: 2 blocks/CU for cross-block overlap (m114 mechanism — waves of
// independent blocks have no shared barrier, so one block's DS window hides
// under the other's MFMA window). Tile 128x256, 8 waves (2Mx4N), per-wave
// 64x64 (acc=64 VGPR -> fits 128-reg budget for 4 waves/SIMD). BK=32 with
// PAIRED-ROW LDS layout [64][64] (128B rows, full 32-bank span) fixing
// r10's 2.5e7 conflicts; slot = chunk ^ (row&7), each 8-lane quarter hits
// 8 distinct slots (conflict-free). Triple buffer 72 KiB (x2 blocks = 144
// <= 160), prefetch distance 2, counted vmcnt(3), ONE barrier per K-tile
// (r10 skeleton, race-proven). T1 XCD swizzle, T5 setprio, r4 fences.

typedef __bf16 bf16_t;
typedef __bf16 bf16x8 __attribute__((ext_vector_type(8)));
typedef float  f32x4  __attribute__((ext_vector_type(4)));

#define M_DIM 8192
#define N_DIM 4096
#define K_DIM 4096
#define NT    (K_DIM / 32)   // 128 K-tiles of BK=32
#define BUFE  12288          // elements per buffer: A 4096 + B 8192 (24 KB)

#define GLD16(gp, lp) __builtin_amdgcn_global_load_lds(                    \
    (const __attribute__((address_space(1))) void*)(gp),                   \
    (__attribute__((address_space(3))) void*)(lp), 16, 0, 0)

#define MFMA(a, b, c) __builtin_amdgcn_mfma_f32_16x16x32_bf16((a), (b), (c), 0, 0, 0)

#define FENCE() asm volatile("" ::: "memory")

// ---------------- fp32 -> bf16 convert (vectorized, grid-stride) -----------
__global__ void __launch_bounds__(256) cvt_f32_bf16(
    const float* __restrict__ in, bf16_t* __restrict__ out, long n8)
{
    long i0 = (long)blockIdx.x * blockDim.x + threadIdx.x;
    long stride = (long)gridDim.x * blockDim.x;
    for (long i = i0; i < n8; i += stride) {
        const float4* p = (const float4*)(in + i * 8);
        float4 a = p[0];
        float4 b = p[1];
        bf16x8 o;
        o[0] = (bf16_t)a.x; o[1] = (bf16_t)a.y; o[2] = (bf16_t)a.z; o[3] = (bf16_t)a.w;
        o[4] = (bf16_t)b.x; o[5] = (bf16_t)b.y; o[6] = (bf16_t)b.z; o[7] = (bf16_t)b.w;
        *(bf16x8*)(out + i * 8) = o;
    }
}

// ---------------- 128x256 bf16 GEMM, 2 blocks/CU, triple-buffer BK=32 ------
// Buffer q: A (128 M-rows x 32 K, paired-row [64][64]) @ q*BUFE,
//           B (256 N-rows x 32 K, paired-row [128][64]) @ q*BUFE + 4096.
// Paired-row: element (m,k) -> lds[(m>>1)*64 + (m&1)*32 + k], swizzled
// slot = chunk ^ (ldsrow & 7) on 16B chunks.
__global__ void __launch_bounds__(512, 4) gemm_128x256(
    const bf16_t* __restrict__ A, const bf16_t* __restrict__ B,
    const float* __restrict__ bias, float* __restrict__ C)
{
    __shared__ bf16_t sm[3 * BUFE];   // 72 KiB -> 2 blocks/CU

    // XCD-aware bijective swizzle (gridDim = 1024, divisible by 8)
    const int nwg = gridDim.x;
    const int bid = blockIdx.x;
    const int cpx = nwg >> 3;
    const int swz = (bid & 7) * cpx + (bid >> 3);
    const int NBN = N_DIM / 256;                       // 16
    const long blockM = (long)(swz / NBN) * 128;
    const long blockN = (long)(swz % NBN) * 256;

    const int t    = threadIdx.x;
    const int lane = t & 63;
    const int wid  = t >> 6;        // 8 waves: 2 (M) x 4 (N)
    const int wr   = wid >> 2;      // 0..1 -> 64 rows each
    const int wc   = wid & 3;       // 0..3 -> 64 cols each
    const int l15  = lane & 15;
    const int lk   = lane >> 4;     // 0..3

    // ---- staging addresses: thread t -> dest chunk t (A) / t, t+512 (B).
    // ldsrow r = t>>3, slot s = t&7, global chunk c = s ^ (r&7),
    // global row = 2r + (c>>2), k-chunk = c&3.
    const int sr = t >> 3;
    const int c  = (t & 7) ^ (sr & 7);
    const int grow = 2 * sr + (c >> 2);
    const int kc8  = (c & 3) * 8;
    const bf16_t* gA  = A + (blockM + grow) * (long)K_DIM + kc8;
    const bf16_t* gB  = B + (blockN + grow) * (long)K_DIM + kc8;
    const bf16_t* gB2 = gB + 128L * K_DIM;
    const int dstT = t * 8;         // 16 B per thread, linear

    // ---- fragment read offsets (elements). Lane (l15, lk) of frag f wants
    // row base+f*16+l15, k = lk*8; paired-row -> ldsrow = base/2 + f*8 +
    // (l15>>1), slot = ((l15&1)*4 + lk) ^ (l15>>1)  [base/2 multiple of 8].
    const int slotA = (((l15 & 1) * 4 + lk) ^ (l15 >> 1)) * 8;
    const int aOff = (wr * 32 + (l15 >> 1)) * 64 + slotA;          // +mf*512
    const int bOff = 4096 + (wc * 32 + (l15 >> 1)) * 64 + slotA;   // +nf*512

    f32x4 acc[4][4] = {};

#define STAGE(q, tk) do {                                                  \
    bf16_t* _l = (bf16_t*)sm + (q) * BUFE + dstT;                          \
    GLD16(gA  + (long)(tk) * 32, _l);                                      \
    GLD16(gB  + (long)(tk) * 32, _l + 4096);                               \
    GLD16(gB2 + (long)(tk) * 32, _l + 8192); } while (0)

    // prologue: tile0 -> buf0, tile1 -> buf1 (fence-pinned issue order)
    STAGE(0, 0);
    FENCE();
    STAGE(1, 1);
    FENCE();
    asm volatile("s_waitcnt vmcnt(3)" ::: "memory");   // tile0 landed
    __builtin_amdgcn_sched_barrier(0);
    __builtin_amdgcn_s_barrier();
    FENCE();

    int r = 0, r2 = 2;   // compute buffer, stage buffer (= (tk+2)%3)
    for (int tk = 0; tk < NT; ++tk) {
        const bf16_t* sA = (const bf16_t*)sm + r * BUFE;

        // stage tile tk+2 into the buffer read last in tile tk-1
        if (tk + 2 < NT) STAGE(r2, tk + 2);
        FENCE();

        // barrier-free window: 8 ds_reads + 16 MFMA (compiler counted waits)
        bf16x8 b[4], a[4];
#pragma unroll
        for (int n = 0; n < 4; ++n) b[n] = *(const bf16x8*)(sA + bOff + n * 512);
#pragma unroll
        for (int m = 0; m < 4; ++m) a[m] = *(const bf16x8*)(sA + aOff + m * 512);
        __builtin_amdgcn_s_setprio(1);
#pragma unroll
        for (int m = 0; m < 4; ++m)
#pragma unroll
            for (int n = 0; n < 4; ++n)
                acc[m][n] = MFMA(a[m], b[n], acc[m][n]);
        __builtin_amdgcn_s_setprio(0);

        // counted drain: tile tk+1's 3 loads land; tk+2's 3 stay in flight
        if (tk < NT - 2) asm volatile("s_waitcnt vmcnt(3)" ::: "memory");
        else             asm volatile("s_waitcnt vmcnt(0)" ::: "memory");
        __builtin_amdgcn_sched_barrier(0);
        __builtin_amdgcn_s_barrier();
        FENCE();

        r  = (r  == 2) ? 0 : r  + 1;
        r2 = (r2 == 2) ? 0 : r2 + 1;
    }

#undef STAGE

    // epilogue: C/D layout col = lane&15, row = (lane>>4)*4 + j
    const long cb = blockN + wc * 64;
    float bv[4];
    long  cn[4];
#pragma unroll
    for (int n = 0; n < 4; ++n) {
        cn[n] = cb + n * 16 + l15;
        bv[n] = bias[cn[n]];
    }
#pragma unroll
    for (int m = 0; m < 4; ++m) {
        const long r0 = blockM + wr * 64 + m * 16 + lk * 4;
#pragma unroll
        for (int n = 0; n < 4; ++n)
#pragma unroll
            for (int j = 0; j < 4; ++j)
                C[(r0 + j) * (long)N_DIM + cn[n]] = acc[m][n][j] + bv[n];
    }
}

// ---------------- fp32 fallback (only if ws too small) ---------------------
__global__ void __launch_bounds__(256) gemm_f32_fallback(
    const float* __restrict__ A, const float* __restrict__ W,
    const float* __restrict__ bias, float* __restrict__ C)
{
    __shared__ float sA[64][17];
    __shared__ float sB[64][17];
    const int bm = blockIdx.y, bn = blockIdx.x;
    const int t = threadIdx.x;
    const int tx = t & 15, ty = t >> 4;
    const long row0 = (long)bm * 64, col0 = (long)bn * 64;
    float acc[4][4] = {};
    for (int kt = 0; kt < K_DIM; kt += 16) {
        const int r = t >> 2, c = (t & 3) * 4;
        float4 a4 = *(const float4*)&A[(row0 + r) * K_DIM + kt + c];
        float4 b4 = *(const float4*)&W[(col0 + r) * K_DIM + kt + c];
        sA[r][c] = a4.x; sA[r][c + 1] = a4.y; sA[r][c + 2] = a4.z; sA[r][c + 3] = a4.w;
        sB[r][c] = b4.x; sB[r][c + 1] = b4.y; sB[r][c + 2] = b4.z; sB[r][c + 3] = b4.w;
        __syncthreads();
#pragma unroll
        for (int kk = 0; kk < 16; ++kk) {
            float av[4], bv[4];
#pragma unroll
            for (int i = 0; i < 4; ++i) av[i] = sA[ty * 4 + i][kk];
#pragma unroll
            for (int j = 0; j < 4; ++j) bv[j] = sB[tx * 4 + j][kk];
#pragma unroll
            for (int i = 0; i < 4; ++i)
#pragma unroll
                for (int j = 0; j < 4; ++j) acc[i][j] += av[i] * bv[j];
        }
        __syncthreads();
    }
#pragma unroll
    for (int i = 0; i < 4; ++i)
#pragma unroll
        for (int j = 0; j < 4; ++j)
            C[(row0 + ty * 4 + i) * N_DIM + col0 + tx * 4 + j] =
                acc[i][j] + bias[col0 + tx * 4 + j];
}

extern "C" void kernel_launch(void* const* d_in, const int* in_sizes, int n_in,
                              void* d_out, int out_size, void* d_ws, size_t ws_size,
                              hipStream_t stream)
{
    const float* x = (const float*)d_in[0];   // [8192, 4096]
    const float* W = (const float*)d_in[1];   // [4096, 4096]
    const float* b = (const float*)d_in[2];   // [4096]
    float* out = (float*)d_out;               // [8192, 4096] fp32

    const long xe = (long)M_DIM * K_DIM;
    const long we = (long)N_DIM * K_DIM;
    const size_t need = (size_t)(xe + we) * sizeof(bf16_t);  // ~96 MiB

    if (ws_size >= need) {
        bf16_t* xb = (bf16_t*)d_ws;
        bf16_t* wb = xb + xe;
        cvt_f32_bf16<<<2048, 256, 0, stream>>>(x, xb, xe / 8);
        cvt_f32_bf16<<<1024, 256, 0, stream>>>(W, wb, we / 8);
        gemm_128x256<<<(M_DIM / 128) * (N_DIM / 256), 512, 0, stream>>>(xb, wb, b, out);
    } else {
        dim3 grid(N_DIM / 64, M_DIM / 64);
        gemm_f32_fallback<<<grid, 256, 0, stream>>>(x, W, b, out);
    }
}

// Round 12
// 281.333 us; speedup vs baseline: 1.1876x; 1.1876x over previous
//
#include <hip/hip_runtime.h>
#include <hip/hip_bf16.h>
#include <stdint.h>

// EvolvedLoopLinear: out[b,j] = sum_i x[b,i]*W[j,i] + b[j]
// M=8192, N=4096, K=4096. fp32 in/out, bf16 MFMA compute.
// Round 12: B bypasses LDS. W is pre-converted into MFMA-fragment-major
// layout (Wf): frag (g=n/16, t2=k/32) is 1 KB contiguous, element (n,k) at
// ((g*128+t2)*64 + lane)*8, lane=(k>>3&3)*16+(n&15). A wave's B-frag is
// ONE coalesced global_load_dwordx4 (L2-resident). This removes 64 KB of
// B traffic per K-tile from the LDS port (serial bottleneck per cycle
// accounting: LDS 2290 + MFMA 2484 = measured 4310 cyc/K-tile) and puts
// it on the concurrent VMEM/L2 pipe. A-path = r9 verbatim (regions, chunk
// swizzle, gld_lds, parity double-buffer, stages P2/P3, counted vmcnt(8)
// ledger re-derived for the mixed VMEM queue). b0(tk+1) loads into b0's
// own regs after q2 (sched_barrier pins order; no rename pressure).

typedef __bf16 bf16_t;
typedef __bf16 bf16x8 __attribute__((ext_vector_type(8)));
typedef float  f32x4  __attribute__((ext_vector_type(4)));

#define M_DIM 8192
#define N_DIM 4096
#define K_DIM 4096
#define NT    (K_DIM / 64)    // 64 K-tiles of BK=64
#define NITER (NT / 2)        // 32 iterations, 2 K-tiles each

#define GLD16(gp, lp) __builtin_amdgcn_global_load_lds(                    \
    (const __attribute__((address_space(1))) void*)(gp),                   \
    (__attribute__((address_space(3))) void*)(lp), 16, 0, 0)

#define MFMA(a, b, c) __builtin_amdgcn_mfma_f32_16x16x32_bf16((a), (b), (c), 0, 0, 0)

#define FENCE() asm volatile("" ::: "memory")

// ---------------- fp32 -> bf16 convert for x (row-major, vectorized) -------
__global__ void __launch_bounds__(256) cvt_f32_bf16(
    const float* __restrict__ in, bf16_t* __restrict__ out, long n8)
{
    long i0 = (long)blockIdx.x * blockDim.x + threadIdx.x;
    long stride = (long)gridDim.x * blockDim.x;
    for (long i = i0; i < n8; i += stride) {
        const float4* p = (const float4*)(in + i * 8);
        float4 a = p[0];
        float4 b = p[1];
        bf16x8 o;
        o[0] = (bf16_t)a.x; o[1] = (bf16_t)a.y; o[2] = (bf16_t)a.z; o[3] = (bf16_t)a.w;
        o[4] = (bf16_t)b.x; o[5] = (bf16_t)b.y; o[6] = (bf16_t)b.z; o[7] = (bf16_t)b.w;
        *(bf16x8*)(out + i * 8) = o;
    }
}

// ---------------- W -> fragment-major bf16 (Wf) -----------------------------
// Wave w = (g, t2): g = w>>7 (n-group of 16), t2 = w&127 (32-k half).
// Lane l: r = l&15 (n offset), c = l>>4 (k-chunk of 8).
// Reads W[g*16+r][t2*32 + c*8 .. +8] (fp32), writes 1 KB contiguous frag.
__global__ void __launch_bounds__(256) cvt_w_frag(
    const float* __restrict__ W, bf16_t* __restrict__ Wf)
{
    long tid = (long)blockIdx.x * blockDim.x + threadIdx.x;
    long wtot = ((long)gridDim.x * blockDim.x) >> 6;
    long w0 = tid >> 6;
    const int lane = (int)(tid & 63);
    const int r = lane & 15, c = lane >> 4;
    for (long w = w0; w < 256L * 128; w += wtot) {
        const long g = w >> 7, t2 = w & 127;
        const float* p = W + (g * 16 + r) * (long)K_DIM + t2 * 32 + c * 8;
        float4 a = *(const float4*)p;
        float4 b = *(const float4*)(p + 4);
        bf16x8 o;
        o[0] = (bf16_t)a.x; o[1] = (bf16_t)a.y; o[2] = (bf16_t)a.z; o[3] = (bf16_t)a.w;
        o[4] = (bf16_t)b.x; o[5] = (bf16_t)b.y; o[6] = (bf16_t)b.z; o[7] = (bf16_t)b.w;
        *(bf16x8*)(Wf + (w * 64 + lane) * 8) = o;
    }
}

// ---------------- 256x256 bf16 GEMM: A via LDS (r9 path), B via regs -------
// LDS per parity buffer q (16384 el): Am0 @0, Am1 @8192. 64 KiB total.
__global__ void __launch_bounds__(512, 1) gemm_256_bg(
    const bf16_t* __restrict__ A, const bf16_t* __restrict__ Wf,
    const float* __restrict__ bias, float* __restrict__ C)
{
    __shared__ bf16_t sm[2 * 16384];   // 64 KiB (A only)

    // XCD-aware bijective swizzle (gridDim = 512, divisible by 8)
    const int nwg = gridDim.x;
    const int bid = blockIdx.x;
    const int cpx = nwg >> 3;
    const int swz = (bid & 7) * cpx + (bid >> 3);
    const int NBN = N_DIM / 256;                       // 16
    const long blockM = (long)(swz / NBN) * 256;
    const long blockN = (long)(swz % NBN) * 256;

    const int t    = threadIdx.x;
    const int lane = t & 63;
    const int wid  = t >> 6;        // 8 waves: 2 (M) x 4 (N)
    const int wr   = wid >> 2;      // 0..1 -> 128 rows each
    const int wc   = wid & 3;       // 0..3 -> 64 cols each
    const int l15  = lane & 15;
    const int lk   = lane >> 4;     // 0..3

    // A staging (r9 verbatim): LDS dest linear, global src carries inverse
    // chunk swizzle; region rho-row mapping.
    const int cg  = (t & 7) ^ ((t >> 3) & 7);
    const int rA0 = (t >> 3);
    const bf16_t* gA = A + (blockM + rA0) * (long)K_DIM + cg * 8;
    const int dstT = t * 8;

    // A fragment reads (r9 verbatim)
    const int swzr = l15 & 7;
    const int cOff0 = ((0 * 4 + lk) ^ swzr) << 3;
    const int cOff1 = ((1 * 4 + lk) ^ swzr) << 3;
    const int aBase = wr * 4096 + l15 * 64;

    // B fragment base: frag (nf, kk, tk) at gW + nf*65536 + (tk*2+kk)*512
    const bf16_t* gW = Wf + ((blockN >> 4) + wc * 4) * 65536L + lane * 8;

    f32x4 acc[8][4] = {};

#define STAGE_A(q, tk, h) do {                                             \
    const bf16_t* _g = gA + (long)(tk) * 64 + (long)(h) * 64 * K_DIM;      \
    bf16_t* _l = (bf16_t*)sm + (q) * 16384 + (h) * 8192 + dstT;            \
    GLD16(_g,                _l);                                          \
    GLD16(_g + 128L * K_DIM, _l + 4096); } while (0)

    bf16x8 a0[4][2], a1[4][2], b0[2][2], b1[2][2];

#define BLD(nf, tk, kk) (*(const bf16x8*)(gW + (long)(nf) * 65536 +        \
                          ((long)(tk) * 2 + (kk)) * 512))

#define LOAD_B0(tk) do {                                                   \
    b0[0][0] = BLD(0, tk, 0); b0[0][1] = BLD(0, tk, 1);                    \
    b0[1][0] = BLD(1, tk, 0); b0[1][1] = BLD(1, tk, 1); } while (0)

#define LOAD_B1(tk) do {                                                   \
    b1[0][0] = BLD(2, tk, 0); b1[0][1] = BLD(2, tk, 1);                    \
    b1[1][0] = BLD(3, tk, 0); b1[1][1] = BLD(3, tk, 1); } while (0)

#define READ_A0(s) do {                                                    \
    _Pragma("unroll") for (int m = 0; m < 4; ++m) {                        \
        a0[m][0] = *(const bf16x8*)((s) + aBase + m * 1024 + cOff0);       \
        a0[m][1] = *(const bf16x8*)((s) + aBase + m * 1024 + cOff1);       \
    } } while (0)

#define READ_A1(s) do {                                                    \
    _Pragma("unroll") for (int m = 0; m < 4; ++m) {                        \
        a1[m][0] = *(const bf16x8*)((s) + 8192 + aBase + m * 1024 + cOff0);\
        a1[m][1] = *(const bf16x8*)((s) + 8192 + aBase + m * 1024 + cOff1);\
    } } while (0)

#define MFMA_Q0() do { _Pragma("unroll") for (int m = 0; m < 4; ++m)       \
    _Pragma("unroll") for (int kk = 0; kk < 2; ++kk)                       \
    _Pragma("unroll") for (int n = 0; n < 2; ++n)                          \
        acc[m][n] = MFMA(a0[m][kk], b0[n][kk], acc[m][n]); } while (0)
#define MFMA_Q1() do { _Pragma("unroll") for (int m = 0; m < 4; ++m)       \
    _Pragma("unroll") for (int kk = 0; kk < 2; ++kk)                       \
    _Pragma("unroll") for (int n = 0; n < 2; ++n)                          \
        acc[m][2 + n] = MFMA(a0[m][kk], b1[n][kk], acc[m][2 + n]); } while (0)
#define MFMA_Q2() do { _Pragma("unroll") for (int m = 0; m < 4; ++m)       \
    _Pragma("unroll") for (int kk = 0; kk < 2; ++kk)                       \
    _Pragma("unroll") for (int n = 0; n < 2; ++n)                          \
        acc[4 + m][n] = MFMA(a1[m][kk], b0[n][kk], acc[4 + m][n]); } while (0)
#define MFMA_Q3() do { _Pragma("unroll") for (int m = 0; m < 4; ++m)       \
    _Pragma("unroll") for (int kk = 0; kk < 2; ++kk)                       \
    _Pragma("unroll") for (int n = 0; n < 2; ++n)                          \
        acc[4 + m][2 + n] = MFMA(a1[m][kk], b1[n][kk], acc[4 + m][2 + n]); } while (0)

#define END_BARRIER()                                                      \
    __builtin_amdgcn_s_barrier();                                          \
    FENCE()

    // prologue. Issue order (fence-pinned): A(t0) 4 | b0(t0) 4 | A(t1) 4.
    // vmcnt(4) retires A(t0)+b0(t0), keeps A(t1) in flight.
    STAGE_A(0, 0, 0); STAGE_A(0, 0, 1);
    FENCE();
    LOAD_B0(0);
    FENCE();
    STAGE_A(1, 1, 0); STAGE_A(1, 1, 1);
    FENCE();
    asm volatile("s_waitcnt vmcnt(4)" ::: "memory");
    __builtin_amdgcn_sched_barrier(0);
    END_BARRIER();

    const bf16_t* s0 = (const bf16_t*)sm;           // buf0 (even tiles)
    const bf16_t* s1 = (const bf16_t*)sm + 16384;   // buf1 (odd tiles)

    for (int i = 0; i < NITER; ++i) {
        const int tk0 = 2 * i;
        const int tk1 = 2 * i + 1;
        const bool full = (i < NITER - 1);

        // ----------------- tile tk0 (buffer s0) -----------------
        // P1: load b1(tk0); read a0; MFMA q0 (b0 = tk0, prefetched)
        LOAD_B1(tk0);
        READ_A0(s0);
        FENCE();
        __builtin_amdgcn_s_setprio(1);
        MFMA_Q0();
        __builtin_amdgcn_s_setprio(0);
        END_BARRIER();

        // P2: read a1; stage Am0(tk0+2 -> s0); MFMA q1
        READ_A1(s0);
        if (full) STAGE_A(0, tk0 + 2, 0);
        FENCE();
        __builtin_amdgcn_s_setprio(1);
        MFMA_Q1();
        __builtin_amdgcn_s_setprio(0);
        END_BARRIER();

        // P3: stage Am1(tk0+2 -> s0); MFMA q2; then load b0(tk1)
        if (full) STAGE_A(0, tk0 + 2, 1);
        FENCE();
        __builtin_amdgcn_s_setprio(1);
        MFMA_Q2();
        __builtin_amdgcn_s_setprio(0);
        __builtin_amdgcn_sched_barrier(0);   // pin q2 (reads old b0) first
        LOAD_B0(tk1);
        FENCE();
        END_BARRIER();

        // P4: MFMA q3; counted drain; barrier
        __builtin_amdgcn_s_setprio(1);
        MFMA_Q3();
        __builtin_amdgcn_s_setprio(0);
        if (full) asm volatile("s_waitcnt vmcnt(8)" ::: "memory");
        else      asm volatile("s_waitcnt vmcnt(4)" ::: "memory");
        __builtin_amdgcn_sched_barrier(0);
        END_BARRIER();

        // ----------------- tile tk1 (buffer s1) -----------------
        // P5: load b1(tk1); read a0; MFMA q0
        LOAD_B1(tk1);
        READ_A0(s1);
        FENCE();
        __builtin_amdgcn_s_setprio(1);
        MFMA_Q0();
        __builtin_amdgcn_s_setprio(0);
        END_BARRIER();

        // P6: read a1; stage Am0(tk1+2 -> s1); MFMA q1
        READ_A1(s1);
        if (full) STAGE_A(1, tk1 + 2, 0);
        FENCE();
        __builtin_amdgcn_s_setprio(1);
        MFMA_Q1();
        __builtin_amdgcn_s_setprio(0);
        END_BARRIER();

        // P7: stage Am1(tk1+2 -> s1); MFMA q2; then load b0(tk1+1)
        if (full) STAGE_A(1, tk1 + 2, 1);
        FENCE();
        __builtin_amdgcn_s_setprio(1);
        MFMA_Q2();
        __builtin_amdgcn_s_setprio(0);
        __builtin_amdgcn_sched_barrier(0);
        if (full) LOAD_B0(tk1 + 1);
        FENCE();
        END_BARRIER();

        // P8: MFMA q3; counted drain; barrier
        __builtin_amdgcn_s_setprio(1);
        MFMA_Q3();
        __builtin_amdgcn_s_setprio(0);
        if (full) asm volatile("s_waitcnt vmcnt(8)" ::: "memory");
        else      asm volatile("s_waitcnt vmcnt(0)" ::: "memory");
        __builtin_amdgcn_sched_barrier(0);
        END_BARRIER();
    }

#undef STAGE_A

    // epilogue: C/D layout col = lane&15, row = (lane>>4)*4 + j
    const long cb = blockN + wc * 64;
    float bv[4];
    long  cn[4];
#pragma unroll
    for (int n = 0; n < 4; ++n) {
        cn[n] = cb + n * 16 + l15;
        bv[n] = bias[cn[n]];
    }
#pragma unroll
    for (int m = 0; m < 8; ++m) {
        const long r0 = blockM + wr * 128 + m * 16 + lk * 4;
#pragma unroll
        for (int n = 0; n < 4; ++n)
#pragma unroll
            for (int j = 0; j < 4; ++j)
                C[(r0 + j) * (long)N_DIM + cn[n]] = acc[m][n][j] + bv[n];
    }
}

// ---------------- fp32 fallback (only if ws too small) ---------------------
__global__ void __launch_bounds__(256) gemm_f32_fallback(
    const float* __restrict__ A, const float* __restrict__ W,
    const float* __restrict__ bias, float* __restrict__ C)
{
    __shared__ float sA[64][17];
    __shared__ float sB[64][17];
    const int bm = blockIdx.y, bn = blockIdx.x;
    const int t = threadIdx.x;
    const int tx = t & 15, ty = t >> 4;
    const long row0 = (long)bm * 64, col0 = (long)bn * 64;
    float acc[4][4] = {};
    for (int kt = 0; kt < K_DIM; kt += 16) {
        const int r = t >> 2, c = (t & 3) * 4;
        float4 a4 = *(const float4*)&A[(row0 + r) * K_DIM + kt + c];
        float4 b4 = *(const float4*)&W[(col0 + r) * K_DIM + kt + c];
        sA[r][c] = a4.x; sA[r][c + 1] = a4.y; sA[r][c + 2] = a4.z; sA[r][c + 3] = a4.w;
        sB[r][c] = b4.x; sB[r][c + 1] = b4.y; sB[r][c + 2] = b4.z; sB[r][c + 3] = b4.w;
        __syncthreads();
#pragma unroll
        for (int kk = 0; kk < 16; ++kk) {
            float av[4], bv[4];
#pragma unroll
            for (int i = 0; i < 4; ++i) av[i] = sA[ty * 4 + i][kk];
#pragma unroll
            for (int j = 0; j < 4; ++j) bv[j] = sB[tx * 4 + j][kk];
#pragma unroll
            for (int i = 0; i < 4; ++i)
#pragma unroll
                for (int j = 0; j < 4; ++j) acc[i][j] += av[i] * bv[j];
        }
        __syncthreads();
    }
#pragma unroll
    for (int i = 0; i < 4; ++i)
#pragma unroll
        for (int j = 0; j < 4; ++j)
            C[(row0 + ty * 4 + i) * N_DIM + col0 + tx * 4 + j] =
                acc[i][j] + bias[col0 + tx * 4 + j];
}

extern "C" void kernel_launch(void* const* d_in, const int* in_sizes, int n_in,
                              void* d_out, int out_size, void* d_ws, size_t ws_size,
                              hipStream_t stream)
{
    const float* x = (const float*)d_in[0];   // [8192, 4096]
    const float* W = (const float*)d_in[1];   // [4096, 4096]
    const float* b = (const float*)d_in[2];   // [4096]
    float* out = (float*)d_out;               // [8192, 4096] fp32

    const long xe = (long)M_DIM * K_DIM;
    const long we = (long)N_DIM * K_DIM;
    const size_t need = (size_t)(xe + we) * sizeof(bf16_t);  // ~96 MiB

    if (ws_size >= need) {
        bf16_t* xb = (bf16_t*)d_ws;
        bf16_t* wf = xb + xe;
        cvt_f32_bf16<<<2048, 256, 0, stream>>>(x, xb, xe / 8);
        cvt_w_frag<<<2048, 256, 0, stream>>>(W, wf);
        gemm_256_bg<<<(M_DIM / 256) * (N_DIM / 256), 512, 0, stream>>>(xb, wf, b, out);
    } else {
        dim3 grid(N_DIM / 64, M_DIM / 64);
        gemm_f32_fallback<<<grid, 256, 0, stream>>>(x, W, b, out);
    }
}